// Round 4
// baseline (32.983 us; speedup 1.0000x reference)
//
#include <hip/hip_runtime.h>

#define TILE 16

// Encode one KAN input value: g = silu(v); U = knot coordinate T=(v-g0)*invh if
// inside the knot span [0,tmax), else -1 (maps to zeroed poly slot 0).
__device__ __forceinline__ float2 kan_enc(float v, float g0, float invh, float tmax) {
    float g = v / (1.0f + __expf(-v));
    float T = (v - g0) * invh;
    float U = (T >= 0.0f && T < tmax) ? T : -1.0f;
    return make_float2(g, U);
}

__device__ __forceinline__ float poly_eval(float4 c, float w) {
    return ((c.w * w + c.z) * w + c.y) * w + c.x;
}

// One piecewise-cubic table entry for interval slot si (si=0 is the zero slot,
// si-1 = knot interval index). Value on interval (w in [0,1)):
//   c0 + c1 w + c2 w^2 + c3 w^3, from the 4 active padded B-spline weights.
__device__ __forceinline__ float4 spline_poly(const float* __restrict__ sw, float sc,
                                              int ncoef, int si) {
    float4 v = make_float4(0.f, 0.f, 0.f, 0.f);
    if (si > 0) {
        int m = si - 1;
        float W[4];
        #pragma unroll
        for (int j = 0; j < 4; ++j) {
            int c = m - 3 + j;
            W[j] = (c >= 0 && c < ncoef) ? sw[c] * sc : 0.0f;
        }
        const float s6 = 1.0f / 6.0f;
        v.x = (W[0] + 4.0f * W[1] + W[2]) * s6;
        v.y = 3.0f * (W[2] - W[0]) * s6;
        v.z = (3.0f * W[0] - 6.0f * W[1] + 3.0f * W[2]) * s6;
        v.w = (W[3] - W[0] + 3.0f * (W[1] - W[2])) * s6;
    }
    return v;
}

// Prologue: build layer2 (180 entries, (k*9+s)*10+si) and layer6 (12 entries,
// at offset 180) poly tables in global scratch — read via L1 by the main kernel.
__global__ void ZS_MKAN_build_tables(const float* __restrict__ spline_w2,
                                     const float* __restrict__ scaler2,
                                     const float* __restrict__ spline_w6,
                                     const float* __restrict__ scaler6,
                                     float4* __restrict__ tab) {
    int e = threadIdx.x;
    if (e < 180) {
        int k = e / 90, r = e % 90, s = r / 10, si = r % 10;
        tab[e] = spline_poly(spline_w2 + (k * 9 + s) * 6, scaler2[k * 9 + s], 6, si);
    } else if (e < 192) {
        tab[e] = spline_poly(spline_w6, scaler6[0], 8, e - 180);
    }
}

template <bool G>
__global__ __launch_bounds__(256) void ZS_MKAN_72121090834671_kernel(
    const float* __restrict__ x,
    const float* __restrict__ base_w1, const float* __restrict__ spline_w1,
    const float* __restrict__ scaler1,
    const float* __restrict__ base_w2, const float* __restrict__ spline_w2,
    const float* __restrict__ scaler2,
    const float* __restrict__ conv_w, const float* __restrict__ conv_b,
    const float* __restrict__ base_w6, const float* __restrict__ spline_w6,
    const float* __restrict__ scaler6,
    const float4* __restrict__ tab,
    float* __restrict__ out)
{
    __shared__ float2 encX[1200];            // x halo transforms: 3ch x 20x20
    __shared__ float2 encY[1944];            // layer1-out transforms: 6ch x 18x18
    __shared__ float4 coefL[2][2][9][10];    // per (layer,k,tap,interval+1) cubic in w
    __shared__ float4 coef6[12];             // layer6: 11 intervals + zero slot
    __shared__ float  sbw[2][18];            // base_w1 / base_w2
    __shared__ float  scw[36], scb[3];       // 1x1 conv
    __shared__ float  sb6;

    const int tid = threadIdx.x;
    const int tx0 = blockIdx.x * TILE;
    const int ty0 = blockIdx.y * TILE;
    const int b   = blockIdx.z;

    // ---- build LDS spline tables (layer1 always; layer2 only if !G) ----
    {
        const int n = G ? 180 : 360;
        for (int e = tid; e < n; e += 256) {
            int l = e / 180, r = e % 180, k = r / 90, r2 = r % 90, s = r2 / 10, si = r2 % 10;
            const float* sw  = l ? spline_w2 : spline_w1;
            const float* scl = l ? scaler2   : scaler1;
            coefL[l][k][s][si] = spline_poly(sw + (k * 9 + s) * 6, scl[k * 9 + s], 6, si);
        }
    }
    if (!G && tid < 12) coef6[tid] = spline_poly(spline_w6, scaler6[0], 8, tid);
    if (tid < 18) { sbw[0][tid] = base_w1[tid]; sbw[1][tid] = base_w2[tid]; }
    if (tid < 36) scw[tid] = conv_w[tid];
    if (tid < 3)  scb[tid] = conv_b[tid];
    if (tid == 0) sb6 = base_w6[0];

    // ---- encode x tile + halo2 (zero-padded values ARE transformed, per ref) ----
    for (int i = tid; i < 1200; i += 256) {
        int c = i / 400, r = i % 400, ly = r / 20, lx = r % 20;
        int gy = ty0 - 2 + ly, gx = tx0 - 2 + lx;
        float v = 0.0f;
        if ((unsigned)gy < 256u && (unsigned)gx < 256u)
            v = x[((b * 3 + c) * 256 + gy) * 256 + gx];
        encX[i] = kan_enc(v, -3.0f, 1.5f, 9.0f);
    }
    __syncthreads();

    // ---- layer1 (3ch -> 6ch) on 18x18, encode outputs directly (LDS tables) ----
    for (int i = tid; i < 972; i += 256) {
        int c = i / 324, r = i % 324, ly = r / 18, lx = r % 18;
        float a0 = 0.0f, a1 = 0.0f;
        int base = c * 400 + ly * 20 + lx;
        #pragma unroll
        for (int s = 0; s < 9; ++s) {
            float2 t = encX[base + (s / 3) * 20 + (s % 3)];
            float mf = floorf(t.y);
            float w  = t.y - mf;
            int  si  = (int)mf + 1;
            a0 += t.x * sbw[0][s]     + poly_eval(coefL[0][0][s][si], w);
            a1 += t.x * sbw[0][9 + s] + poly_eval(coefL[0][1][s][si], w);
        }
        int gy = ty0 - 1 + ly, gx = tx0 - 1 + lx;
        if (!((unsigned)gy < 256u && (unsigned)gx < 256u)) { a0 = 0.0f; a1 = 0.0f; }
        encY[(c * 2 + 0) * 324 + r] = kan_enc(a0, -3.0f, 1.5f, 9.0f);
        encY[(c * 2 + 1) * 324 + r] = kan_enc(a1, -3.0f, 1.5f, 9.0f);
    }
    __syncthreads();

    // ---- layer2 (6 -> 12), one output pixel per thread (L1 tables when G) ----
    const int ly = tid >> 4, lx = tid & 15;
    float z[12];
    #pragma unroll
    for (int c = 0; c < 6; ++c) {
        float a0 = 0.0f, a1 = 0.0f;
        int base = c * 324 + ly * 18 + lx;
        #pragma unroll
        for (int s = 0; s < 9; ++s) {
            float2 t = encY[base + (s / 3) * 18 + (s % 3)];
            float mf = floorf(t.y);
            float w  = t.y - mf;
            int  si  = (int)mf + 1;
            float4 q0, q1;
            if constexpr (G) {
                q0 = tab[s * 10 + si];          // k=0
                q1 = tab[(9 + s) * 10 + si];    // k=1
            } else {
                q0 = coefL[1][0][s][si];
                q1 = coefL[1][1][s][si];
            }
            a0 += t.x * sbw[1][s]     + poly_eval(q0, w);
            a1 += t.x * sbw[1][9 + s] + poly_eval(q1, w);
        }
        z[2 * c]     = a0;
        z[2 * c + 1] = a1;
    }

    // ---- 1x1 conv (12->3) + pointwise KAN layer6 + store ----
    const int gy = ty0 + ly, gx = tx0 + lx;
    #pragma unroll
    for (int o = 0; o < 3; ++o) {
        float v = scb[o];
        #pragma unroll
        for (int c = 0; c < 12; ++c) v += scw[o * 12 + c] * z[c];
        float2 t = kan_enc(v, -2.2f, 2.5f, 11.0f);
        float mf = floorf(t.y);
        float w  = t.y - mf;
        int  si  = (int)mf + 1;
        float4 c6 = G ? tab[180 + si] : coef6[si];
        out[((b * 3 + o) * 256 + gy) * 256 + gx] = t.x * sb6 + poly_eval(c6, w);
    }
}

extern "C" void kernel_launch(void* const* d_in, const int* in_sizes, int n_in,
                              void* d_out, int out_size, void* d_ws, size_t ws_size,
                              hipStream_t stream) {
    (void)in_sizes; (void)n_in; (void)out_size;
    const float* x         = (const float*)d_in[0];
    const float* base_w1   = (const float*)d_in[1];
    const float* spline_w1 = (const float*)d_in[2];
    const float* scaler1   = (const float*)d_in[3];
    const float* base_w2   = (const float*)d_in[4];
    const float* spline_w2 = (const float*)d_in[5];
    const float* scaler2   = (const float*)d_in[6];
    const float* conv_w    = (const float*)d_in[7];
    const float* conv_b    = (const float*)d_in[8];
    const float* base_w6   = (const float*)d_in[9];
    const float* spline_w6 = (const float*)d_in[10];
    const float* scaler6   = (const float*)d_in[11];
    float* out = (float*)d_out;

    dim3 grid(256 / TILE, 256 / TILE, 4);
    dim3 block(256);

    if (ws_size >= 192 * sizeof(float4)) {
        float4* tab = (float4*)d_ws;
        ZS_MKAN_build_tables<<<1, 192, 0, stream>>>(spline_w2, scaler2,
                                                    spline_w6, scaler6, tab);
        ZS_MKAN_72121090834671_kernel<true><<<grid, block, 0, stream>>>(
            x, base_w1, spline_w1, scaler1, base_w2, spline_w2, scaler2,
            conv_w, conv_b, base_w6, spline_w6, scaler6, tab, out);
    } else {
        ZS_MKAN_72121090834671_kernel<false><<<grid, block, 0, stream>>>(
            x, base_w1, spline_w1, scaler1, base_w2, spline_w2, scaler2,
            conv_w, conv_b, base_w6, spline_w6, scaler6, nullptr, out);
    }
}

// Round 5
// 27.433 us; speedup vs baseline: 1.2023x; 1.2023x over previous
//
#include <hip/hip_runtime.h>
#include <hip/hip_fp16.h>

#define TILE 16

// Encode one KAN input value: g = silu(v); U = knot coordinate T=(v-g0)*invh if
// inside the knot span [0,tmax), else -1 (maps to zeroed poly slot 0).
__device__ __forceinline__ float2 kan_enc(float v, float g0, float invh, float tmax) {
    float g = v / (1.0f + __expf(-v));
    float T = (v - g0) * invh;
    float U = (T >= 0.0f && T < tmax) ? T : -1.0f;
    return make_float2(g, U);
}

__device__ __forceinline__ float poly_eval(float4 c, float w) {
    return ((c.w * w + c.z) * w + c.y) * w + c.x;
}

// One piecewise-cubic table entry for interval slot si (si=0 is the zero slot,
// si-1 = knot interval index). Value on interval (w in [0,1)):
//   c0 + c1 w + c2 w^2 + c3 w^3, from the 4 active padded B-spline weights.
__device__ __forceinline__ float4 spline_poly(const float* __restrict__ sw, float sc,
                                              int ncoef, int si) {
    float4 v = make_float4(0.f, 0.f, 0.f, 0.f);
    if (si > 0) {
        int m = si - 1;
        float W[4];
        #pragma unroll
        for (int j = 0; j < 4; ++j) {
            int c = m - 3 + j;
            W[j] = (c >= 0 && c < ncoef) ? sw[c] * sc : 0.0f;
        }
        const float s6 = 1.0f / 6.0f;
        v.x = (W[0] + 4.0f * W[1] + W[2]) * s6;
        v.y = 3.0f * (W[2] - W[0]) * s6;
        v.z = (3.0f * W[0] - 6.0f * W[1] + 3.0f * W[2]) * s6;
        v.w = (W[3] - W[0] + 3.0f * (W[1] - W[2])) * s6;
    }
    return v;
}

union H2U { __half2 h; unsigned u; };
__device__ __forceinline__ unsigned pack_h2(float a, float b) {
    H2U t; t.h = __halves2half2(__float2half_rn(a), __float2half_rn(b));
    return t.u;
}
__device__ __forceinline__ float2 unpack_h2(unsigned u) {
    H2U t; t.u = u;
    return __half22float2(t.h);
}

__global__ __launch_bounds__(256) void ZS_MKAN_72121090834671_kernel(
    const float* __restrict__ x,
    const float* __restrict__ base_w1, const float* __restrict__ spline_w1,
    const float* __restrict__ scaler1,
    const float* __restrict__ base_w2, const float* __restrict__ spline_w2,
    const float* __restrict__ scaler2,
    const float* __restrict__ conv_w, const float* __restrict__ conv_b,
    const float* __restrict__ base_w6, const float* __restrict__ spline_w6,
    const float* __restrict__ scaler6,
    float* __restrict__ out)
{
    __shared__ float2 encX[1200];         // x halo transforms: 3ch x 20x20
    __shared__ float4 encY2[3][324];      // layer1 out pairs (g0,U0,g1,U1), 18x18
    __shared__ float4 coefL[2][9][10];    // layer1 f32 cubic per (k,tap,slot)
    __shared__ uint4  coefH[9][10];       // layer2 f16x8: k0{c0..c3}, k1{c0..c3}
    __shared__ float4 coef6[12];          // layer6: 11 intervals + zero slot
    __shared__ float  sbw[2][18];         // base_w1 / base_w2
    __shared__ float  scw[36], scb[3];    // 1x1 conv
    __shared__ float  sb6;

    const int tid = threadIdx.x;
    const int tx0 = blockIdx.x * TILE;
    const int ty0 = blockIdx.y * TILE;
    const int b   = blockIdx.z;

    // ---- build spline tables ----
    for (int e = tid; e < 180; e += 256) {          // layer1, f32
        int k = e / 90, r = e % 90, s = r / 10, si = r % 10;
        coefL[k][s][si] = spline_poly(spline_w1 + (k * 9 + s) * 6,
                                      scaler1[k * 9 + s], 6, si);
    }
    for (int e = tid; e < 90; e += 256) {           // layer2, f16 k-pair packed
        int s = e / 10, si = e % 10;
        float4 a = spline_poly(spline_w2 + s * 6,        scaler2[s],     6, si);
        float4 c = spline_poly(spline_w2 + (9 + s) * 6,  scaler2[9 + s], 6, si);
        uint4 q;
        q.x = pack_h2(a.x, a.y); q.y = pack_h2(a.z, a.w);
        q.z = pack_h2(c.x, c.y); q.w = pack_h2(c.z, c.w);
        coefH[s][si] = q;
    }
    if (tid < 12) coef6[tid] = spline_poly(spline_w6, scaler6[0], 8, tid);
    if (tid < 18) { sbw[0][tid] = base_w1[tid]; sbw[1][tid] = base_w2[tid]; }
    if (tid < 36) scw[tid] = conv_w[tid];
    if (tid < 3)  scb[tid] = conv_b[tid];
    if (tid == 0) sb6 = base_w6[0];

    // ---- encode x tile + halo2 (zero-padded values ARE transformed, per ref) ----
    for (int i = tid; i < 1200; i += 256) {
        int c = i / 400, r = i % 400, ly = r / 20, lx = r % 20;
        int gy = ty0 - 2 + ly, gx = tx0 - 2 + lx;
        float v = 0.0f;
        if ((unsigned)gy < 256u && (unsigned)gx < 256u)
            v = x[((b * 3 + c) * 256 + gy) * 256 + gx];
        encX[i] = kan_enc(v, -3.0f, 1.5f, 9.0f);
    }
    __syncthreads();

    // ---- layer1 (3ch -> 6ch) on 18x18, encode channel-paired outputs ----
    for (int i = tid; i < 972; i += 256) {
        int c = i / 324, r = i % 324, ly = r / 18, lx = r % 18;
        float a0 = 0.0f, a1 = 0.0f;
        int base = c * 400 + ly * 20 + lx;
        #pragma unroll
        for (int s = 0; s < 9; ++s) {
            float2 t = encX[base + (s / 3) * 20 + (s % 3)];
            float mf = floorf(t.y);
            float w  = t.y - mf;
            int  si  = (int)mf + 1;
            a0 += t.x * sbw[0][s]     + poly_eval(coefL[0][s][si], w);
            a1 += t.x * sbw[0][9 + s] + poly_eval(coefL[1][s][si], w);
        }
        int gy = ty0 - 1 + ly, gx = tx0 - 1 + lx;
        if (!((unsigned)gy < 256u && (unsigned)gx < 256u)) { a0 = 0.0f; a1 = 0.0f; }
        float2 e0 = kan_enc(a0, -3.0f, 1.5f, 9.0f);
        float2 e1 = kan_enc(a1, -3.0f, 1.5f, 9.0f);
        encY2[c][r] = make_float4(e0.x, e0.y, e1.x, e1.y);
    }
    __syncthreads();

    // ---- layer2 (6 -> 12), one output pixel per thread ----
    const int ly = tid >> 4, lx = tid & 15;
    float z[12];
    #pragma unroll
    for (int c = 0; c < 3; ++c) {        // pair of y-channels (2c, 2c+1)
        float a00 = 0.0f, a01 = 0.0f, a10 = 0.0f, a11 = 0.0f;
        #pragma unroll
        for (int s = 0; s < 9; ++s) {
            float4 e = encY2[c][(ly + s / 3) * 18 + lx + (s % 3)];
            float bw0 = sbw[1][s], bw1 = sbw[1][9 + s];
            {   // channel h=0: (g,U) = (e.x, e.y)
                float mf = floorf(e.y);
                float w  = e.y - mf;
                int  si  = (int)mf + 1;
                uint4 q = coefH[s][si];
                float2 p0 = unpack_h2(q.x), p1 = unpack_h2(q.y);
                float2 p2 = unpack_h2(q.z), p3 = unpack_h2(q.w);
                a00 += e.x * bw0 + (((p1.y * w + p1.x) * w + p0.y) * w + p0.x);
                a01 += e.x * bw1 + (((p3.y * w + p3.x) * w + p2.y) * w + p2.x);
            }
            {   // channel h=1: (g,U) = (e.z, e.w)
                float mf = floorf(e.w);
                float w  = e.w - mf;
                int  si  = (int)mf + 1;
                uint4 q = coefH[s][si];
                float2 p0 = unpack_h2(q.x), p1 = unpack_h2(q.y);
                float2 p2 = unpack_h2(q.z), p3 = unpack_h2(q.w);
                a10 += e.z * bw0 + (((p1.y * w + p1.x) * w + p0.y) * w + p0.x);
                a11 += e.z * bw1 + (((p3.y * w + p3.x) * w + p2.y) * w + p2.x);
            }
        }
        z[4 * c + 0] = a00; z[4 * c + 1] = a01;
        z[4 * c + 2] = a10; z[4 * c + 3] = a11;
    }

    // ---- 1x1 conv (12->3) + pointwise KAN layer6 + store ----
    const int gy = ty0 + ly, gx = tx0 + lx;
    #pragma unroll
    for (int o = 0; o < 3; ++o) {
        float v = scb[o];
        #pragma unroll
        for (int c = 0; c < 12; ++c) v += scw[o * 12 + c] * z[c];
        float2 t = kan_enc(v, -2.2f, 2.5f, 11.0f);
        float mf = floorf(t.y);
        float w  = t.y - mf;
        int  si  = (int)mf + 1;
        out[((b * 3 + o) * 256 + gy) * 256 + gx] = t.x * sb6 + poly_eval(coef6[si], w);
    }
}

extern "C" void kernel_launch(void* const* d_in, const int* in_sizes, int n_in,
                              void* d_out, int out_size, void* d_ws, size_t ws_size,
                              hipStream_t stream) {
    (void)in_sizes; (void)n_in; (void)d_ws; (void)ws_size; (void)out_size;
    const float* x         = (const float*)d_in[0];
    const float* base_w1   = (const float*)d_in[1];
    const float* spline_w1 = (const float*)d_in[2];
    const float* scaler1   = (const float*)d_in[3];
    const float* base_w2   = (const float*)d_in[4];
    const float* spline_w2 = (const float*)d_in[5];
    const float* scaler2   = (const float*)d_in[6];
    const float* conv_w    = (const float*)d_in[7];
    const float* conv_b    = (const float*)d_in[8];
    const float* base_w6   = (const float*)d_in[9];
    const float* spline_w6 = (const float*)d_in[10];
    const float* scaler6   = (const float*)d_in[11];
    float* out = (float*)d_out;

    dim3 grid(256 / TILE, 256 / TILE, 4);
    dim3 block(256);
    ZS_MKAN_72121090834671_kernel<<<grid, block, 0, stream>>>(
        x, base_w1, spline_w1, scaler1, base_w2, spline_w2, scaler2,
        conv_w, conv_b, base_w6, spline_w6, scaler6, out);
}

// Round 7
// 21.444 us; speedup vs baseline: 1.5381x; 1.2793x over previous
//
#include <hip/hip_runtime.h>
#include <hip/hip_fp16.h>

#define TILE 16

typedef __fp16 h2f __attribute__((ext_vector_type(2)));

union H2U { h2f h; unsigned u; __half2 hh; };

__device__ __forceinline__ h2f u2h(unsigned u) { H2U t; t.u = u; return t.h; }

__device__ __forceinline__ unsigned pack_h2(float a, float b) {
    H2U t; t.hh = __halves2half2(__float2half_rn(a), __float2half_rn(b));
    return t.u;
}

// dot2: acc += a.x*b.x + a.y*b.y (f16 mul, f32 acc) — V_DOT2_F32_F16
__device__ __forceinline__ float fdot2(h2f a, h2f b, float acc) {
#if __has_builtin(__builtin_amdgcn_fdot2)
    return __builtin_amdgcn_fdot2(a, b, acc, false);
#else
    return acc + (float)a.x * (float)b.x + (float)a.y * (float)b.y;
#endif
}

// Encode one KAN input value: g = silu(v); U = knot coordinate T=(v-g0)*invh if
// inside the knot span [0,tmax), else -1 (maps to zeroed poly slot 0).
__device__ __forceinline__ float2 kan_enc(float v, float g0, float invh, float tmax) {
    float g = v / (1.0f + __expf(-v));
    float T = (v - g0) * invh;
    float U = (T >= 0.0f && T < tmax) ? T : -1.0f;
    return make_float2(g, U);
}

__device__ __forceinline__ float poly_eval(float4 c, float w) {
    return ((c.w * w + c.z) * w + c.y) * w + c.x;
}

// One piecewise-cubic table entry for interval slot si (si=0 is the zero slot,
// si-1 = knot interval index). Value on interval (w in [0,1)):
//   c0 + c1 w + c2 w^2 + c3 w^3, from the 4 active padded B-spline weights.
__device__ __forceinline__ float4 spline_poly(const float* __restrict__ sw, float sc,
                                              int ncoef, int si) {
    float4 v = make_float4(0.f, 0.f, 0.f, 0.f);
    if (si > 0) {
        int m = si - 1;
        float W[4];
        #pragma unroll
        for (int j = 0; j < 4; ++j) {
            int c = m - 3 + j;
            W[j] = (c >= 0 && c < ncoef) ? sw[c] * sc : 0.0f;
        }
        const float s6 = 1.0f / 6.0f;
        v.x = (W[0] + 4.0f * W[1] + W[2]) * s6;
        v.y = 3.0f * (W[2] - W[0]) * s6;
        v.z = (3.0f * W[0] - 6.0f * W[1] + 3.0f * W[2]) * s6;
        v.w = (W[3] - W[0] + 3.0f * (W[1] - W[2])) * s6;
    }
    return v;
}

__global__ __launch_bounds__(256) void ZS_MKAN_72121090834671_kernel(
    const float* __restrict__ x,
    const float* __restrict__ base_w1, const float* __restrict__ spline_w1,
    const float* __restrict__ scaler1,
    const float* __restrict__ base_w2, const float* __restrict__ spline_w2,
    const float* __restrict__ scaler2,
    const float* __restrict__ conv_w, const float* __restrict__ conv_b,
    const float* __restrict__ base_w6, const float* __restrict__ spline_w6,
    const float* __restrict__ scaler6,
    float* __restrict__ out)
{
    __shared__ float2 encX[1200];         // x halo transforms: 3ch x 20x20
    __shared__ float4 encY2[3][324];      // layer1 out pairs (g0,U0,g1,U1), 18x18
    __shared__ uint4  coefH1[9][10];      // layer1 f16x8: k0{c0..c3}, k1{c0..c3}
    __shared__ uint4  coefH2[9][10];      // layer2 f16x8
    __shared__ float4 coef6[12];          // layer6: 11 intervals + zero slot (f32)
    __shared__ float  sbw[2][18];         // base_w1 / base_w2
    __shared__ float  scw[36], scb[3];    // 1x1 conv
    __shared__ float  sb6;

    const int tid = threadIdx.x;
    const int tx0 = blockIdx.x * TILE;
    const int ty0 = blockIdx.y * TILE;
    const int b   = blockIdx.z;

    // ---- build f16 k-pair-packed spline tables for both conv layers ----
    for (int e = tid; e < 180; e += 256) {
        int l = e / 90, r = e % 90, s = r / 10, si = r % 10;
        const float* sw  = l ? spline_w2 : spline_w1;
        const float* scl = l ? scaler2   : scaler1;
        float4 a = spline_poly(sw + s * 6,       scl[s],     6, si);
        float4 c = spline_poly(sw + (9 + s) * 6, scl[9 + s], 6, si);
        uint4 q;
        q.x = pack_h2(a.x, a.y); q.y = pack_h2(a.z, a.w);
        q.z = pack_h2(c.x, c.y); q.w = pack_h2(c.z, c.w);
        if (l) coefH2[s][si] = q; else coefH1[s][si] = q;
    }
    if (tid < 12) coef6[tid] = spline_poly(spline_w6, scaler6[0], 8, tid);
    if (tid < 18) { sbw[0][tid] = base_w1[tid]; sbw[1][tid] = base_w2[tid]; }
    if (tid < 36) scw[tid] = conv_w[tid];
    if (tid < 3)  scb[tid] = conv_b[tid];
    if (tid == 0) sb6 = base_w6[0];

    // ---- encode x tile + halo2 (zero-padded values ARE transformed, per ref) ----
    for (int i = tid; i < 1200; i += 256) {
        int c = i / 400, r = i % 400, ly = r / 20, lx = r % 20;
        int gy = ty0 - 2 + ly, gx = tx0 - 2 + lx;
        float v = 0.0f;
        if ((unsigned)gy < 256u && (unsigned)gx < 256u)
            v = x[((b * 3 + c) * 256 + gy) * 256 + gx];
        encX[i] = kan_enc(v, -3.0f, 1.5f, 9.0f);
    }
    __syncthreads();

    // ---- layer1 (3ch -> 6ch) on 18x18, encode channel-paired outputs ----
    for (int i = tid; i < 972; i += 256) {
        int c = i / 324, r = i % 324, ly = r / 18, lx = r % 18;
        float a0 = 0.0f, a1 = 0.0f;
        int base = c * 400 + ly * 20 + lx;
        #pragma unroll
        for (int s = 0; s < 9; ++s) {
            float2 t = encX[base + (s / 3) * 20 + (s % 3)];
            float mf = floorf(t.y);
            float w  = t.y - mf;
            int  si  = (int)mf + 1;
            float w2 = w * w;
            h2f p1 = __builtin_amdgcn_cvt_pkrtz(1.0f, w);
            h2f p2 = __builtin_amdgcn_cvt_pkrtz(w2, w2 * w);
            uint4 q = coefH1[s][si];
            a0 += t.x * sbw[0][s];
            a1 += t.x * sbw[0][9 + s];
            a0 = fdot2(u2h(q.x), p1, a0); a0 = fdot2(u2h(q.y), p2, a0);
            a1 = fdot2(u2h(q.z), p1, a1); a1 = fdot2(u2h(q.w), p2, a1);
        }
        int gy = ty0 - 1 + ly, gx = tx0 - 1 + lx;
        if (!((unsigned)gy < 256u && (unsigned)gx < 256u)) { a0 = 0.0f; a1 = 0.0f; }
        float2 e0 = kan_enc(a0, -3.0f, 1.5f, 9.0f);
        float2 e1 = kan_enc(a1, -3.0f, 1.5f, 9.0f);
        encY2[c][r] = make_float4(e0.x, e0.y, e1.x, e1.y);
    }
    __syncthreads();

    // ---- layer2 (6 -> 12), one output pixel per thread ----
    const int ly = tid >> 4, lx = tid & 15;
    float z[12];
    #pragma unroll
    for (int c = 0; c < 3; ++c) {        // pair of y-channels (2c, 2c+1)
        float a00 = 0.0f, a01 = 0.0f, a10 = 0.0f, a11 = 0.0f;
        #pragma unroll
        for (int s = 0; s < 9; ++s) {
            float4 e = encY2[c][(ly + s / 3) * 18 + lx + (s % 3)];
            float bw0 = sbw[1][s], bw1 = sbw[1][9 + s];
            {   // channel h=0: (g,U) = (e.x, e.y)
                float mf = floorf(e.y);
                float w  = e.y - mf;
                int  si  = (int)mf + 1;
                float w2 = w * w;
                h2f p1 = __builtin_amdgcn_cvt_pkrtz(1.0f, w);
                h2f p2 = __builtin_amdgcn_cvt_pkrtz(w2, w2 * w);
                uint4 q = coefH2[s][si];
                a00 += e.x * bw0;
                a01 += e.x * bw1;
                a00 = fdot2(u2h(q.x), p1, a00); a00 = fdot2(u2h(q.y), p2, a00);
                a01 = fdot2(u2h(q.z), p1, a01); a01 = fdot2(u2h(q.w), p2, a01);
            }
            {   // channel h=1: (g,U) = (e.z, e.w)
                float mf = floorf(e.w);
                float w  = e.w - mf;
                int  si  = (int)mf + 1;
                float w2 = w * w;
                h2f p1 = __builtin_amdgcn_cvt_pkrtz(1.0f, w);
                h2f p2 = __builtin_amdgcn_cvt_pkrtz(w2, w2 * w);
                uint4 q = coefH2[s][si];
                a10 += e.z * bw0;
                a11 += e.z * bw1;
                a10 = fdot2(u2h(q.x), p1, a10); a10 = fdot2(u2h(q.y), p2, a10);
                a11 = fdot2(u2h(q.z), p1, a11); a11 = fdot2(u2h(q.w), p2, a11);
            }
        }
        z[4 * c + 0] = a00; z[4 * c + 1] = a01;
        z[4 * c + 2] = a10; z[4 * c + 3] = a11;
    }

    // ---- 1x1 conv (12->3) + pointwise KAN layer6 (f32) + store ----
    const int gy = ty0 + ly, gx = tx0 + lx;
    #pragma unroll
    for (int o = 0; o < 3; ++o) {
        float v = scb[o];
        #pragma unroll
        for (int c = 0; c < 12; ++c) v += scw[o * 12 + c] * z[c];
        float2 t = kan_enc(v, -2.2f, 2.5f, 11.0f);
        float mf = floorf(t.y);
        float w  = t.y - mf;
        int  si  = (int)mf + 1;
        out[((b * 3 + o) * 256 + gy) * 256 + gx] = t.x * sb6 + poly_eval(coef6[si], w);
    }
}

extern "C" void kernel_launch(void* const* d_in, const int* in_sizes, int n_in,
                              void* d_out, int out_size, void* d_ws, size_t ws_size,
                              hipStream_t stream) {
    (void)in_sizes; (void)n_in; (void)d_ws; (void)ws_size; (void)out_size;
    const float* x         = (const float*)d_in[0];
    const float* base_w1   = (const float*)d_in[1];
    const float* spline_w1 = (const float*)d_in[2];
    const float* scaler1   = (const float*)d_in[3];
    const float* base_w2   = (const float*)d_in[4];
    const float* spline_w2 = (const float*)d_in[5];
    const float* scaler2   = (const float*)d_in[6];
    const float* conv_w    = (const float*)d_in[7];
    const float* conv_b    = (const float*)d_in[8];
    const float* base_w6   = (const float*)d_in[9];
    const float* spline_w6 = (const float*)d_in[10];
    const float* scaler6   = (const float*)d_in[11];
    float* out = (float*)d_out;

    dim3 grid(256 / TILE, 256 / TILE, 4);
    dim3 block(256);
    ZS_MKAN_72121090834671_kernel<<<grid, block, 0, stream>>>(
        x, base_w1, spline_w1, scaler1, base_w2, spline_w2, scaler2,
        conv_w, conv_b, base_w6, spline_w6, scaler6, out);
}

// Round 8
// 21.358 us; speedup vs baseline: 1.5443x; 1.0041x over previous
//
#include <hip/hip_runtime.h>
#include <hip/hip_fp16.h>

#define TILE 16

typedef __fp16 h2f __attribute__((ext_vector_type(2)));

union H2U { h2f h; unsigned u; __half2 hh; };

__device__ __forceinline__ h2f u2h(unsigned u) { H2U t; t.u = u; return t.h; }

__device__ __forceinline__ unsigned pack_h2(float a, float b) {
    H2U t; t.hh = __halves2half2(__float2half_rn(a), __float2half_rn(b));
    return t.u;
}

// dot2: acc += a.x*b.x + a.y*b.y (f16 mul, f32 acc) — V_DOT2_F32_F16
__device__ __forceinline__ float fdot2(h2f a, h2f b, float acc) {
#if __has_builtin(__builtin_amdgcn_fdot2)
    return __builtin_amdgcn_fdot2(a, b, acc, false);
#else
    return acc + (float)a.x * (float)b.x + (float)a.y * (float)b.y;
#endif
}

// Encode one KAN input: g=silu(v); knot coord T=(v-g0)*invh; w=frac, si=interval
// slot (0 => out-of-span zero slot; 1..tmax => interval floor(T)).
struct Enc { float g, w; int si; };
__device__ __forceinline__ Enc kan_enc3(float v, float g0, float invh, float tmax) {
    Enc e;
    e.g = v / (1.0f + __expf(-v));
    float T = (v - g0) * invh;
    float U = (T >= 0.0f && T < tmax) ? T : -1.0f;
    float mf = floorf(U);
    e.w = U - mf;          // 0 when out of span
    e.si = (int)mf + 1;    // 0 when out of span
    return e;
}

__device__ __forceinline__ float poly_eval(float4 c, float w) {
    return ((c.w * w + c.z) * w + c.y) * w + c.x;
}

// Piecewise-cubic table entry for interval slot si (si=0 zero slot).
__device__ __forceinline__ float4 spline_poly(const float* __restrict__ sw, float sc,
                                              int ncoef, int si) {
    float4 v = make_float4(0.f, 0.f, 0.f, 0.f);
    if (si > 0) {
        int m = si - 1;
        float W[4];
        #pragma unroll
        for (int j = 0; j < 4; ++j) {
            int c = m - 3 + j;
            W[j] = (c >= 0 && c < ncoef) ? sw[c] * sc : 0.0f;
        }
        const float s6 = 1.0f / 6.0f;
        v.x = (W[0] + 4.0f * W[1] + W[2]) * s6;
        v.y = 3.0f * (W[2] - W[0]) * s6;
        v.z = (3.0f * W[0] - 6.0f * W[1] + 3.0f * W[2]) * s6;
        v.w = (W[3] - W[0] + 3.0f * (W[1] - W[2])) * s6;
    }
    return v;
}

__global__ __launch_bounds__(256) void ZS_MKAN_72121090834671_kernel(
    const float* __restrict__ x,
    const float* __restrict__ base_w1, const float* __restrict__ spline_w1,
    const float* __restrict__ scaler1,
    const float* __restrict__ base_w2, const float* __restrict__ spline_w2,
    const float* __restrict__ scaler2,
    const float* __restrict__ conv_w, const float* __restrict__ conv_b,
    const float* __restrict__ base_w6, const float* __restrict__ spline_w6,
    const float* __restrict__ scaler6,
    float* __restrict__ out)
{
    __shared__ float2  encXg[1200];        // (g,w) per x-halo pixel, 3ch x 20x20
    __shared__ unsigned short encXs[1200]; // si per x-halo pixel
    __shared__ float4  encYg[3][324];      // (g0,w0,g1,w1) layer1-out pairs, 18x18
    __shared__ ushort2 encYs[3][324];      // (si0,si1)
    __shared__ uint4   coefH1[9][10];      // layer1 f16x8: k0{c0..c3}, k1{c0..c3}
    __shared__ uint4   coefH2[9][10];      // layer2 f16x8
    __shared__ float4  coef6[12];          // layer6 f32: 11 intervals + zero slot
    __shared__ float   sbw[2][18];         // base_w1 / base_w2
    __shared__ float   scw[36], scb[3];    // 1x1 conv
    __shared__ float   sb6;

    const int tid = threadIdx.x;
    const int tx0 = blockIdx.x * TILE;
    const int ty0 = blockIdx.y * TILE;
    const int b   = blockIdx.z;

    // ---- build f16 k-pair-packed spline tables for both conv layers ----
    for (int e = tid; e < 180; e += 256) {
        int l = e / 90, r = e % 90, s = r / 10, si = r % 10;
        const float* sw  = l ? spline_w2 : spline_w1;
        const float* scl = l ? scaler2   : scaler1;
        float4 a = spline_poly(sw + s * 6,       scl[s],     6, si);
        float4 c = spline_poly(sw + (9 + s) * 6, scl[9 + s], 6, si);
        uint4 q;
        q.x = pack_h2(a.x, a.y); q.y = pack_h2(a.z, a.w);
        q.z = pack_h2(c.x, c.y); q.w = pack_h2(c.z, c.w);
        if (l) coefH2[s][si] = q; else coefH1[s][si] = q;
    }
    if (tid < 12) coef6[tid] = spline_poly(spline_w6, scaler6[0], 8, tid);
    if (tid < 18) { sbw[0][tid] = base_w1[tid]; sbw[1][tid] = base_w2[tid]; }
    if (tid < 36) scw[tid] = conv_w[tid];
    if (tid < 3)  scb[tid] = conv_b[tid];
    if (tid == 0) sb6 = base_w6[0];

    // ---- encode x tile + halo2 (zero-padded values ARE transformed, per ref) ----
    for (int i = tid; i < 1200; i += 256) {
        int c = i / 400, r = i % 400, ly = r / 20, lx = r % 20;
        int gy = ty0 - 2 + ly, gx = tx0 - 2 + lx;
        float v = 0.0f;
        if ((unsigned)gy < 256u && (unsigned)gx < 256u)
            v = x[((b * 3 + c) * 256 + gy) * 256 + gx];
        Enc e = kan_enc3(v, -3.0f, 1.5f, 9.0f);
        encXg[i] = make_float2(e.g, e.w);
        encXs[i] = (unsigned short)e.si;
    }
    __syncthreads();

    // ---- layer1 (3ch -> 6ch) on 18x18, encode channel-paired outputs ----
    {
        float rb0[9], rb1[9];
        #pragma unroll
        for (int s = 0; s < 9; ++s) { rb0[s] = sbw[0][s]; rb1[s] = sbw[0][9 + s]; }
        for (int i = tid; i < 972; i += 256) {
            int c = i / 324, r = i % 324, ly = r / 18, lx = r % 18;
            float a0 = 0.0f, a1 = 0.0f;
            int base = c * 400 + ly * 20 + lx;
            #pragma unroll
            for (int s = 0; s < 9; ++s) {
                int p = base + (s / 3) * 20 + (s % 3);
                float2 gw = encXg[p];
                int si = encXs[p];
                uint4 q = coefH1[s][si];
                float w = gw.y, w2 = w * w;
                h2f p1 = __builtin_amdgcn_cvt_pkrtz(1.0f, w);
                h2f p2 = __builtin_amdgcn_cvt_pkrtz(w2, w2 * w);
                a0 += gw.x * rb0[s];
                a1 += gw.x * rb1[s];
                a0 = fdot2(u2h(q.x), p1, a0); a0 = fdot2(u2h(q.y), p2, a0);
                a1 = fdot2(u2h(q.z), p1, a1); a1 = fdot2(u2h(q.w), p2, a1);
            }
            int gy = ty0 - 1 + ly, gx = tx0 - 1 + lx;
            if (!((unsigned)gy < 256u && (unsigned)gx < 256u)) { a0 = 0.0f; a1 = 0.0f; }
            Enc e0 = kan_enc3(a0, -3.0f, 1.5f, 9.0f);
            Enc e1 = kan_enc3(a1, -3.0f, 1.5f, 9.0f);
            encYg[c][r] = make_float4(e0.g, e0.w, e1.g, e1.w);
            encYs[c][r] = make_ushort2((unsigned short)e0.si, (unsigned short)e1.si);
        }
    }
    __syncthreads();

    // ---- layer2 (6 -> 12), one output pixel per thread ----
    const int ly = tid >> 4, lx = tid & 15;
    float z[12];
    {
        float rb0[9], rb1[9];
        #pragma unroll
        for (int s = 0; s < 9; ++s) { rb0[s] = sbw[1][s]; rb1[s] = sbw[1][9 + s]; }
        const int rbase = ly * 18 + lx;
        #pragma unroll
        for (int c = 0; c < 3; ++c) {    // pair of y-channels (2c, 2c+1)
            float a00 = 0.0f, a01 = 0.0f, a10 = 0.0f, a11 = 0.0f;
            #pragma unroll
            for (int s = 0; s < 9; ++s) {
                int p = rbase + (s / 3) * 18 + (s % 3);
                float4 e = encYg[c][p];
                ushort2 ss = encYs[c][p];
                uint4 q0 = coefH2[s][ss.x];
                uint4 q1 = coefH2[s][ss.y];
                {   // channel h=0
                    float w = e.y, w2 = w * w;
                    h2f p1 = __builtin_amdgcn_cvt_pkrtz(1.0f, w);
                    h2f p2 = __builtin_amdgcn_cvt_pkrtz(w2, w2 * w);
                    a00 += e.x * rb0[s];
                    a01 += e.x * rb1[s];
                    a00 = fdot2(u2h(q0.x), p1, a00); a00 = fdot2(u2h(q0.y), p2, a00);
                    a01 = fdot2(u2h(q0.z), p1, a01); a01 = fdot2(u2h(q0.w), p2, a01);
                }
                {   // channel h=1
                    float w = e.w, w2 = w * w;
                    h2f p1 = __builtin_amdgcn_cvt_pkrtz(1.0f, w);
                    h2f p2 = __builtin_amdgcn_cvt_pkrtz(w2, w2 * w);
                    a10 += e.z * rb0[s];
                    a11 += e.z * rb1[s];
                    a10 = fdot2(u2h(q1.x), p1, a10); a10 = fdot2(u2h(q1.y), p2, a10);
                    a11 = fdot2(u2h(q1.z), p1, a11); a11 = fdot2(u2h(q1.w), p2, a11);
                }
            }
            z[4 * c + 0] = a00; z[4 * c + 1] = a01;
            z[4 * c + 2] = a10; z[4 * c + 3] = a11;
        }
    }

    // ---- 1x1 conv (12->3) + pointwise KAN layer6 (f32) + store ----
    const int gy = ty0 + ly, gx = tx0 + lx;
    #pragma unroll
    for (int o = 0; o < 3; ++o) {
        float v = scb[o];
        #pragma unroll
        for (int c = 0; c < 12; ++c) v += scw[o * 12 + c] * z[c];
        Enc t = kan_enc3(v, -2.2f, 2.5f, 11.0f);
        out[((b * 3 + o) * 256 + gy) * 256 + gx] = t.g * sb6 + poly_eval(coef6[t.si], t.w);
    }
}

extern "C" void kernel_launch(void* const* d_in, const int* in_sizes, int n_in,
                              void* d_out, int out_size, void* d_ws, size_t ws_size,
                              hipStream_t stream) {
    (void)in_sizes; (void)n_in; (void)d_ws; (void)ws_size; (void)out_size;
    const float* x         = (const float*)d_in[0];
    const float* base_w1   = (const float*)d_in[1];
    const float* spline_w1 = (const float*)d_in[2];
    const float* scaler1   = (const float*)d_in[3];
    const float* base_w2   = (const float*)d_in[4];
    const float* spline_w2 = (const float*)d_in[5];
    const float* scaler2   = (const float*)d_in[6];
    const float* conv_w    = (const float*)d_in[7];
    const float* conv_b    = (const float*)d_in[8];
    const float* base_w6   = (const float*)d_in[9];
    const float* spline_w6 = (const float*)d_in[10];
    const float* scaler6   = (const float*)d_in[11];
    float* out = (float*)d_out;

    dim3 grid(256 / TILE, 256 / TILE, 4);
    dim3 block(256);
    ZS_MKAN_72121090834671_kernel<<<grid, block, 0, stream>>>(
        x, base_w1, spline_w1, scaler1, base_w2, spline_w2, scaler2,
        conv_w, conv_b, base_w6, spline_w6, scaler6, out);
}